// Round 1
// baseline (1032.179 us; speedup 1.0000x reference)
//
#include <hip/hip_runtime.h>
#include <hip/hip_bf16.h>

#define DIM 300

using shortx4 = __attribute__((ext_vector_type(4))) short;
using shortx8 = __attribute__((ext_vector_type(8))) short;
using floatx4 = __attribute__((ext_vector_type(4))) float;

__device__ __forceinline__ short f2bf(float f) {
  union { __hip_bfloat16 h; short s; } u;
  u.h = __float2bfloat16(f);
  return u.s;
}

// Pack Ws (fp32 [5][300][300], row n = out-feature, col k = in-feature) into
// bf16 MFMA B-fragments in d_ws. B[k][n] = W[n][k]. Padded: n->304 (19 tiles
// of 16), k->320 (10 iters of 32), zeros in the pad.
// frag(s,nt,kk) is 1KB: lane l holds the 8 contiguous bf16
// W[n = nt*16 + (l&15)][k = kk*32 + (l>>4)*8 + j], j=0..7.
// Fragment loads in the main kernel are thus 16B/lane fully coalesced.
__global__ void prep_w_kernel(const float* __restrict__ Ws, short* __restrict__ wsB) {
  int t = blockIdx.x * 256 + threadIdx.x;
  if (t >= 5 * 19 * 10 * 64) return;
  int fid = t >> 6, lane = t & 63;
  int s = fid / 190; int rem = fid - s * 190;
  int nt = rem / 10; int kk = rem - nt * 10;
  int n  = nt * 16 + (lane & 15);
  int k0 = kk * 32 + (lane >> 4) * 8;
  shortx8 v;
  #pragma unroll
  for (int j = 0; j < 8; ++j) {
    int k = k0 + j;
    float f = (n < DIM && k < DIM) ? Ws[s * (DIM * DIM) + n * DIM + k] : 0.0f;
    v[j] = f2bf(f);
  }
  *reinterpret_cast<shortx8*>(wsB + (size_t)fid * 512 + lane * 8) = v;
}

// One block = 64 consecutive groups of scale R, full N (300, padded 304).
// LDS A tile: [64 rows][328 bf16] (K padded 300->320, +8 pad => row stride
// 656B = 164 dwords, 164%32=4 -> only 2-way bank aliasing on b128 reads = free).
template <int R>
__device__ __forceinline__ void run_tile(
    const float* __restrict__ x, const float* __restrict__ bs,
    float* __restrict__ out, const short* __restrict__ wsB,
    int si, int tile, int N, short* A)
{
  const int tid = threadIdx.x;
  const int groups = N / R;                  // N divisible by all scales
  const int g0 = tile * 64;
  int validM = groups - g0; if (validM > 64) validM = 64;

  // ---- Stage A: fp32 group sums -> bf16 LDS. 64 rows x 82 float4-slots
  // (75 real + pad). Consecutive threads -> consecutive 16B chunks (coalesced).
  // R is a template constant: the r-loop fully unrolls -> R independent loads
  // in flight per slot.
  for (int idx = tid; idx < 64 * 82; idx += 256) {
    int m  = idx / 82;
    int kv = idx - m * 82;
    float ax = 0.f, ay = 0.f, az = 0.f, aw = 0.f;
    if (kv < 75 && m < validM) {
      const float* p = x + ((size_t)(g0 + m) * R) * DIM + kv * 4;
      #pragma unroll
      for (int j = 0; j < R; ++j) {
        float4 v = *reinterpret_cast<const float4*>(p + j * DIM);
        ax += v.x; ay += v.y; az += v.z; aw += v.w;
      }
    }
    shortx4 h;
    h[0] = f2bf(ax); h[1] = f2bf(ay); h[2] = f2bf(az); h[3] = f2bf(aw);
    *reinterpret_cast<shortx4*>(&A[m * 328 + kv * 4]) = h;
  }
  __syncthreads();

  // ---- MFMA: wave w owns rows [w*16, w*16+16); loops 19 n-tiles x 10 k-iters.
  const int lane = tid & 63;
  const int wave = tid >> 6;
  const int lr   = lane & 15;
  const int quad = lane >> 4;
  const int wm   = wave * 16;

  // Preload all 10 A fragments once (A[m=lane&15][k=quad*8+j], 16B ds_read).
  shortx8 af[10];
  #pragma unroll
  for (int kk = 0; kk < 10; ++kk)
    af[kk] = *reinterpret_cast<const shortx8*>(&A[(wm + lr) * 328 + kk * 32 + quad * 8]);

  const float inv_r = 1.0f / (float)R;
  const short* wb = wsB + (size_t)si * 190 * 512 + lane * 8;
  float* outS = out + (size_t)si * N * DIM;

  #pragma unroll 1
  for (int nt = 0; nt < 19; ++nt) {
    floatx4 acc = {0.f, 0.f, 0.f, 0.f};
    const short* wnt = wb + nt * 10 * 512;
    #pragma unroll
    for (int kk = 0; kk < 10; ++kk) {
      shortx8 bf = *reinterpret_cast<const shortx8*>(wnt + kk * 512);
      acc = __builtin_amdgcn_mfma_f32_16x16x32_bf16(af[kk], bf, acc, 0, 0, 0);
    }
    // C/D layout: col = lane&15, row = quad*4 + reg  [measured m89/m91]
    const int n = nt * 16 + lr;
    if (n < DIM) {
      const float b = bs[si * DIM + n];
      #pragma unroll
      for (int j = 0; j < 4; ++j) {
        const int m = wm + quad * 4 + j;
        if (m < validM) {
          float v = acc[j] + b;
          v = v > 0.f ? v * inv_r : 0.f;
          float* p = outS + ((size_t)(g0 + m) * R) * DIM + n;
          #pragma unroll
          for (int rep = 0; rep < R; ++rep) p[rep * DIM] = v;
        }
      }
    }
  }
}

__global__ __launch_bounds__(256) void ce_main_kernel(
    const float* __restrict__ x, const float* __restrict__ bs,
    float* __restrict__ out, const short* __restrict__ wsB,
    int N, int b0, int b1, int b2, int b3)
{
  __shared__ __align__(16) short A[64 * 328];
  const int bid = blockIdx.x;
  // Grid ordered descending r so long-staging r=25 blocks launch first.
  if (bid < b0)      run_tile<25>(x, bs, out, wsB, 4, bid,      N, A);
  else if (bid < b1) run_tile<10>(x, bs, out, wsB, 3, bid - b0, N, A);
  else if (bid < b2) run_tile<4> (x, bs, out, wsB, 2, bid - b1, N, A);
  else if (bid < b3) run_tile<2> (x, bs, out, wsB, 1, bid - b2, N, A);
  else               run_tile<1> (x, bs, out, wsB, 0, bid - b3, N, A);
}

extern "C" void kernel_launch(void* const* d_in, const int* in_sizes, int n_in,
                              void* d_out, int out_size, void* d_ws, size_t ws_size,
                              hipStream_t stream) {
  const float* x  = (const float*)d_in[0];
  const float* Ws = (const float*)d_in[1];
  const float* bs = (const float*)d_in[2];
  float* out = (float*)d_out;
  short* wsB = (short*)d_ws;                 // needs 972,800 B of scratch

  const int N = in_sizes[0] / DIM;           // 100000

  // B-fragment precompute (bf16 swizzled W), 60800 threads.
  prep_w_kernel<<<(5 * 19 * 10 * 64 + 255) / 256, 256, 0, stream>>>(Ws, wsB);

  // Tile counts per scale, grid ordered r = 25,10,4,2,1.
  const int t25 = (N / 25 + 63) / 64;
  const int t10 = (N / 10 + 63) / 64;
  const int t4  = (N / 4  + 63) / 64;
  const int t2  = (N / 2  + 63) / 64;
  const int t1  = (N      + 63) / 64;
  const int b0 = t25;
  const int b1 = b0 + t10;
  const int b2 = b1 + t4;
  const int b3 = b2 + t2;
  const int total = b3 + t1;

  ce_main_kernel<<<total, 256, 0, stream>>>(x, bs, out, wsB, N, b0, b1, b2, b3);
}

// Round 3
// 800.174 us; speedup vs baseline: 1.2899x; 1.2899x over previous
//
#include <hip/hip_runtime.h>
#include <hip/hip_bf16.h>

#define DIM 300

using shortx4 = __attribute__((ext_vector_type(4))) short;
using shortx8 = __attribute__((ext_vector_type(8))) short;
using floatx4 = __attribute__((ext_vector_type(4))) float;

__device__ __forceinline__ short f2bf(float f) {
  union { __hip_bfloat16 h; short s; } u;
  u.h = __float2bfloat16(f);
  return u.s;
}

// Pack Ws (fp32 [5][300][300], row n = out-feature, col k = in-feature) into
// bf16 MFMA B-fragments in d_ws. B[k][n] = W[n][k]. Padded: n->304 (19 tiles
// of 16), k->320 (10 iters of 32), zeros in the pad.
// frag(s,nt,kk) is 1KB: lane l holds the 8 contiguous bf16
// W[n = nt*16 + (l&15)][k = kk*32 + (l>>4)*8 + j], j=0..7.
__global__ void prep_w_kernel(const float* __restrict__ Ws, short* __restrict__ wsB) {
  int t = blockIdx.x * 256 + threadIdx.x;
  if (t >= 5 * 19 * 10 * 64) return;
  int fid = t >> 6, lane = t & 63;
  int s = fid / 190; int rem = fid - s * 190;
  int nt = rem / 10; int kk = rem - nt * 10;
  int n  = nt * 16 + (lane & 15);
  int k0 = kk * 32 + (lane >> 4) * 8;
  shortx8 v;
  #pragma unroll
  for (int j = 0; j < 8; ++j) {
    int k = k0 + j;
    float f = (n < DIM && k < DIM) ? Ws[s * (DIM * DIM) + n * DIM + k] : 0.0f;
    v[j] = f2bf(f);
  }
  *reinterpret_cast<shortx8*>(wsB + (size_t)fid * 512 + lane * 8) = v;
}

// One block = 64 consecutive groups of scale R, full N (300->304 n-tiles).
// LDS A: [64][328] bf16 (41984 B) staging; reused after fragment preload as
// the h-tile Stage [64][312] bf16. Expansion writes are fully dense float4
// (row = exactly 75 float4, no pad) -> 1KB per wave store instruction.
template <int R>
__device__ __forceinline__ void run_tile(
    const float* __restrict__ x, const float* __restrict__ bs,
    float* __restrict__ out, const short* __restrict__ wsB,
    int si, int tile, int N, short* A, float* bsh)
{
  const int tid = threadIdx.x;
  const int groups = N / R;                  // N divisible by all scales
  const int g0 = tile * 64;
  int validM = groups - g0; if (validM > 64) validM = 64;

  // Bias -> LDS. NOTE: 304 > blockDim(256) -> MUST stride (R2 bug: tail
  // bsh[256..303] was uninitialized garbage -> wrong bias for cols 256..299).
  for (int t = tid; t < 304; t += 256) bsh[t] = (t < DIM) ? bs[si * DIM + t] : 0.0f;

  // ---- Stage A: fp32 group sums -> bf16 LDS. 64 rows x 82 float4-slots.
  for (int idx = tid; idx < 64 * 82; idx += 256) {
    int m  = idx / 82;
    int kv = idx - m * 82;
    float ax = 0.f, ay = 0.f, az = 0.f, aw = 0.f;
    if (kv < 75 && m < validM) {
      const float* p = x + ((size_t)(g0 + m) * R) * DIM + kv * 4;
      #pragma unroll
      for (int j = 0; j < R; ++j) {
        float4 v = *reinterpret_cast<const float4*>(p + j * DIM);
        ax += v.x; ay += v.y; az += v.z; aw += v.w;
      }
    }
    shortx4 h;
    h[0] = f2bf(ax); h[1] = f2bf(ay); h[2] = f2bf(az); h[3] = f2bf(aw);
    *reinterpret_cast<shortx4*>(&A[m * 328 + kv * 4]) = h;
  }
  __syncthreads();

  // ---- Preload all 10 A fragments (A[m=wm+lr][k=kk*32+quad*8+j], 16B reads).
  const int lane = tid & 63;
  const int wave = tid >> 6;
  const int lr   = lane & 15;
  const int quad = lane >> 4;
  const int wm   = wave * 16;

  shortx8 af[10];
  #pragma unroll
  for (int kk = 0; kk < 10; ++kk)
    af[kk] = *reinterpret_cast<const shortx8*>(&A[(wm + lr) * 328 + kk * 32 + quad * 8]);
  __syncthreads();          // preload drained by barrier; A reusable as Stage.

  short* Stage = A;         // [64][312] bf16, 39936 B <= 41984 B
  const float inv_r = 1.0f / (float)R;
  const short* wb = wsB + (size_t)si * 190 * 512 + lane * 8;

  #pragma unroll 1
  for (int nt = 0; nt < 19; ++nt) {
    floatx4 acc = {0.f, 0.f, 0.f, 0.f};
    const short* wnt = wb + nt * 10 * 512;
    #pragma unroll
    for (int kk = 0; kk < 10; ++kk) {
      shortx8 bf = *reinterpret_cast<const shortx8*>(wnt + kk * 512);
      acc = __builtin_amdgcn_mfma_f32_16x16x32_bf16(af[kk], bf, acc, 0, 0, 0);
    }
    // C/D layout: col = lane&15, row = quad*4 + reg  [m89/m91]
    const int n = nt * 16 + lr;                 // <= 303, always in bsh/Stage
    const float b = bsh[n];
    #pragma unroll
    for (int j = 0; j < 4; ++j) {
      float v = acc[j] + b;
      v = v > 0.f ? v * inv_r : 0.f;
      Stage[(wm + quad * 4 + j) * 312 + n] = f2bf(v);
    }
  }
  __syncthreads();

  // ---- Expansion: dense float4 stores over the block's contiguous range.
  // out rows [g0*R, g0*R + validM*R) of scale si; 300 floats = 75 float4/row.
  float4* __restrict__ outv =
      reinterpret_cast<float4*>(out) + ((size_t)si * N + (size_t)g0 * R) * 75;
  const int total = validM * R * 75;
  for (int f = tid; f < total; f += 256) {
    int mr = f / 75;                  // out-row within block
    int c  = f - mr * 75;             // float4 col
    int sm = mr / R;                  // source h row (const div)
    int2 d = *reinterpret_cast<const int2*>(&Stage[sm * 312 + c * 4]);
    float4 o;
    o.x = __uint_as_float(((unsigned)d.x) << 16);
    o.y = __uint_as_float(((unsigned)d.x) & 0xffff0000u);
    o.z = __uint_as_float(((unsigned)d.y) << 16);
    o.w = __uint_as_float(((unsigned)d.y) & 0xffff0000u);
    outv[f] = o;
  }
}

__global__ __launch_bounds__(256) void ce_main_kernel(
    const float* __restrict__ x, const float* __restrict__ bs,
    float* __restrict__ out, const short* __restrict__ wsB,
    int N, int b0, int b1, int b2, int b3)
{
  __shared__ __align__(16) short A[64 * 328];
  __shared__ float bsh[304];
  const int bid = blockIdx.x;
  // Grid ordered descending r so the heavy r=25 blocks launch first.
  if (bid < b0)      run_tile<25>(x, bs, out, wsB, 4, bid,      N, A, bsh);
  else if (bid < b1) run_tile<10>(x, bs, out, wsB, 3, bid - b0, N, A, bsh);
  else if (bid < b2) run_tile<4> (x, bs, out, wsB, 2, bid - b1, N, A, bsh);
  else if (bid < b3) run_tile<2> (x, bs, out, wsB, 1, bid - b2, N, A, bsh);
  else               run_tile<1> (x, bs, out, wsB, 0, bid - b3, N, A, bsh);
}

extern "C" void kernel_launch(void* const* d_in, const int* in_sizes, int n_in,
                              void* d_out, int out_size, void* d_ws, size_t ws_size,
                              hipStream_t stream) {
  const float* x  = (const float*)d_in[0];
  const float* Ws = (const float*)d_in[1];
  const float* bs = (const float*)d_in[2];
  float* out = (float*)d_out;
  short* wsB = (short*)d_ws;                 // 972,800 B of scratch

  const int N = in_sizes[0] / DIM;           // 100000

  prep_w_kernel<<<(5 * 19 * 10 * 64 + 255) / 256, 256, 0, stream>>>(Ws, wsB);

  const int t25 = (N / 25 + 63) / 64;
  const int t10 = (N / 10 + 63) / 64;
  const int t4  = (N / 4  + 63) / 64;
  const int t2  = (N / 2  + 63) / 64;
  const int t1  = (N      + 63) / 64;
  const int b0 = t25;
  const int b1 = b0 + t10;
  const int b2 = b1 + t4;
  const int b3 = b2 + t2;
  const int total = b3 + t1;

  ce_main_kernel<<<total, 256, 0, stream>>>(x, bs, out, wsB, N, b0, b1, b2, b3);
}